// Round 2
// baseline (4979.059 us; speedup 1.0000x reference)
//
#include <hip/hip_runtime.h>

// Residual 2-layer LSTM, T=256 B=64 H=1024, fp32 io, bf16 MFMA compute.
//
// R5 = R4 (fused 256-WG persistent kernel, layer5 on WGs 0-127, layer6 on
// WGs 128-255, software-pipelined one step apart) + latency-cut bundle:
//
//  1. SINGLE flag per layer-5 step: out5b is computed (h + x residual, fp32)
//     and stored in the SAME vmcnt(0)+barrier window as h5, under flags5[t].
//     flagsO is gone; L5's second publish block (extra drain+barrier+flag)
//     is gone; out5[t] becomes visible to L6 ~2k cycles earlier.
//  2. PER-WAVE producer-subset polling: consumer wave w's K-slice
//     [256w,256w+256) comes only from producer WGs [32w,32w+32). Each wave
//     polls its own 32 flags (lanes 0-31) and proceeds independently -- no
//     release __syncthreads, straggler set 128 -> 32, early waves overlap
//     their LLC h-reads with sibling waves' waits. Layer6 does one 64-lane
//     poll: lanes 0-31 on flags5[t] subset, lanes 32-63 on flags6[t-1]
//     subset. L6's residual read of out5b (own cols) is safe: it happens
//     after the gp __syncthreads, by which the 4 waves collectively
//     confirmed all 128 flags5[t].
//  3. s_sleep(2) -> s_sleep(1).
//
// Coherence (one dispatch, no boundary flush):
//  - h5/h6/out5b written with AGENT-scope 4B stores + vmcnt(0) drain before
//    the flag store. Reader-side cached loads are safe: addresses are virgin
//    within the dispatch (written once agent-scope -> LLC, read after).

#define TT 256
#define BB 64
#define HH 1024
#define GG 128
#define BH (BB * HH)

typedef __attribute__((ext_vector_type(8))) short short8;
typedef __attribute__((ext_vector_type(4))) float float4v;
typedef __attribute__((ext_vector_type(2))) float float2v;

__device__ __forceinline__ unsigned short f2bf(float f) {
  unsigned u = __builtin_bit_cast(unsigned, f);
  u += 0x7fffu + ((u >> 16) & 1u);
  return (unsigned short)(u >> 16);
}
__device__ __forceinline__ float bf2f(unsigned short s) {
  unsigned u = ((unsigned)s) << 16;
  return __builtin_bit_cast(float, u);
}
__device__ __forceinline__ float fexp2(float x) { return __builtin_amdgcn_exp2f(x); }
__device__ __forceinline__ float frcp(float x) { return __builtin_amdgcn_rcpf(x); }
__device__ __forceinline__ float sigm(float x) {
  return frcp(1.0f + fexp2(-1.4426950408889634f * x));
}
__device__ __forceinline__ float tanha(float x) {
  return 1.0f - 2.0f * frcp(1.0f + fexp2(2.8853900817779268f * x));
}

__global__ __launch_bounds__(256, 1) void lstm2_fused(
    const float* __restrict__ x,
    const float* __restrict__ wih5, const float* __restrict__ whh5,
    const float* __restrict__ bih5, const float* __restrict__ bhh5,
    const float* __restrict__ wih6, const float* __restrict__ whh6,
    const float* __restrict__ bih6, const float* __restrict__ bhh6,
    unsigned short* __restrict__ out5b, unsigned short* __restrict__ hbuf5,
    unsigned short* __restrict__ hbuf6, float* __restrict__ out,
    int* __restrict__ flags5, int* __restrict__ flags6) {
  const int role = (int)(blockIdx.x >> 7); // 0 = layer5, 1 = layer6
  const int p = (int)(blockIdx.x & 127);   // column block (8 h-cols)
  const int tid = threadIdx.x;
  const int w = tid >> 6;
  const int lane = tid & 63;
  const int ln = lane & 15;
  const int q = lane >> 4;

  __shared__ float gp[4][BB][35];

  const float* wih = role ? wih6 : wih5;
  const float* whh = role ? whh6 : whh5;
  const float* bih = role ? bih6 : bih5;
  const float* bhh = role ? bhh6 : bhh5;

  // ---- persistent weight fragments: this wave covers k in [256w, 256w+256)
  // wf[kk*2+nt]: n = 16*nt+ln, k = 256*w + kk*32 + 8*q + j
  short8 wfx[16], wfh[16];
#pragma unroll
  for (int kk = 0; kk < 8; ++kk) {
#pragma unroll
    for (int nt = 0; nt < 2; ++nt) {
      const int n = 16 * nt + ln;
      const int gidx = (n >> 3) * HH + p * 8 + (n & 7); // gate order i,f,g,o
      const int k0 = 256 * w + kk * 32 + 8 * q;
      const float* sx = wih + (size_t)gidx * HH + k0;
      const float* sh = whh + (size_t)gidx * HH + k0;
      short8 vx, vh;
#pragma unroll
      for (int j = 0; j < 8; ++j) { vx[j] = (short)f2bf(sx[j]); vh[j] = (short)f2bf(sh[j]); }
      wfx[kk * 2 + nt] = vx;
      wfh[kk * 2 + nt] = vh;
    }
  }

  // ---- elementwise state: thread owns (b=lane, cols 2w and 2w+1)
  const int eb = lane;
  const int jj0 = w;
  float bsum[2][4];
#pragma unroll
  for (int s = 0; s < 2; ++s) {
    const int jj = 2 * jj0 + s;
#pragma unroll
    for (int gt = 0; gt < 4; ++gt) {
      const int gidx = gt * HH + p * 8 + jj;
      bsum[s][gt] = bih[gidx] + bhh[gidx];
    }
  }
  float cst[2] = {0.f, 0.f};

  // ---- A-operand offsets
  size_t rh[4];  // blocked bf16 layout [t][col>>3][b][col&7]
  size_t rxf[4]; // fp32 row-major [t][b][h] (layer5 x)
#pragma unroll
  for (int mt = 0; mt < 4; ++mt) {
    rh[mt] = (size_t)(16 * mt + ln) * 8 + (size_t)(256 * w + 8 * q) * 64;
    rxf[mt] = (size_t)(16 * mt + ln) * HH + (size_t)(256 * w + 8 * q);
  }

  for (int t = 0; t < TT; ++t) {
    float4v acc[4][2];
#pragma unroll
    for (int mt = 0; mt < 4; ++mt)
#pragma unroll
      for (int nt = 0; nt < 2; ++nt)
        acc[mt][nt] = (float4v){0.f, 0.f, 0.f, 0.f};

    const size_t tb = (size_t)t * BH;
    const size_t hidx = tb + (size_t)p * 512 + (size_t)eb * 8 + 2 * jj0;
    float2v rres; // layer5 x-residual, prefetched before the wait

    if (role == 0) {
      // residual prefetch (read-only, no cross-WG dependency)
      rres = *(const float2v*)(x + tb + (size_t)eb * HH + p * 8 + 2 * jj0);
      // ---- layer5 x-part: fp32 x, cvt on the fly (overlaps producers' tails)
      const float* Xb = x + tb;
#pragma unroll
      for (int kk = 0; kk < 8; ++kk) {
        short8 af[4];
#pragma unroll
        for (int mt = 0; mt < 4; ++mt) {
          const float* sx = Xb + rxf[mt] + 32 * kk;
          const float4v a = *(const float4v*)sx;
          const float4v b = *(const float4v*)(sx + 4);
          short8 v;
          v[0] = (short)f2bf(a[0]); v[1] = (short)f2bf(a[1]);
          v[2] = (short)f2bf(a[2]); v[3] = (short)f2bf(a[3]);
          v[4] = (short)f2bf(b[0]); v[5] = (short)f2bf(b[1]);
          v[6] = (short)f2bf(b[2]); v[7] = (short)f2bf(b[3]);
          af[mt] = v;
        }
#pragma unroll
        for (int mt = 0; mt < 4; ++mt) {
          acc[mt][0] = __builtin_amdgcn_mfma_f32_16x16x32_bf16(af[mt], wfx[kk * 2 + 0], acc[mt][0], 0, 0, 0);
          acc[mt][1] = __builtin_amdgcn_mfma_f32_16x16x32_bf16(af[mt], wfx[kk * 2 + 1], acc[mt][1], 0, 0, 0);
        }
      }
      // per-wave gate: this wave's h-slice producers are WGs [32w, 32w+32)
      if (t > 0) {
        const int* fl = flags5 + (size_t)(t - 1) * GG + 32 * w;
        for (;;) {
          int f = 1;
          if (lane < 32)
            f = __hip_atomic_load(fl + lane, __ATOMIC_RELAXED, __HIP_MEMORY_SCOPE_AGENT);
          if (__all(f != 0)) break;
          __builtin_amdgcn_s_sleep(1);
        }
        __builtin_amdgcn_fence(__ATOMIC_ACQUIRE, "workgroup"); // compiler order only
      }
    } else {
      // ---- layer6 per-wave gate: out5[t] slice (lanes 0-31 poll flags5[t])
      // AND own h6[t-1] slice (lanes 32-63 poll flags6[t-1]); both subsets
      // are this wave's 32 producers [32w, 32w+32).
      {
        const int* fo = flags5 + (size_t)t * GG + 32 * w;
        const int* fh = flags6 + (size_t)(t > 0 ? t - 1 : 0) * GG + 32 * w;
        for (;;) {
          int f = 1;
          if (lane < 32)
            f = __hip_atomic_load(fo + lane, __ATOMIC_RELAXED, __HIP_MEMORY_SCOPE_AGENT);
          else if (t > 0)
            f = __hip_atomic_load(fh + (lane - 32), __ATOMIC_RELAXED, __HIP_MEMORY_SCOPE_AGENT);
          if (__all(f != 0)) break;
          __builtin_amdgcn_s_sleep(1);
        }
        __builtin_amdgcn_fence(__ATOMIC_ACQUIRE, "workgroup"); // compiler order only
      }
      // ---- layer6 x-part: out5b blocked bf16 (cached; virgin addrs -> LLC-fresh)
      const unsigned short* Ab = out5b + tb;
#pragma unroll
      for (int kk = 0; kk < 8; ++kk) {
        short8 af[4];
#pragma unroll
        for (int mt = 0; mt < 4; ++mt)
          af[mt] = *(const short8*)(Ab + rh[mt] + (size_t)kk * 2048);
#pragma unroll
        for (int mt = 0; mt < 4; ++mt) {
          acc[mt][0] = __builtin_amdgcn_mfma_f32_16x16x32_bf16(af[mt], wfx[kk * 2 + 0], acc[mt][0], 0, 0, 0);
          acc[mt][1] = __builtin_amdgcn_mfma_f32_16x16x32_bf16(af[mt], wfx[kk * 2 + 1], acc[mt][1], 0, 0, 0);
        }
      }
    }

    // ---- h-part (per-wave gating already done above)
    if (t > 0) {
      const unsigned short* Hb = (role ? hbuf6 : hbuf5) + (size_t)(t - 1) * BH;
#pragma unroll
      for (int kk = 0; kk < 8; ++kk) {
        short8 af[4];
#pragma unroll
        for (int mt = 0; mt < 4; ++mt)
          af[mt] = *(const short8*)(Hb + rh[mt] + (size_t)kk * 2048); // cached
#pragma unroll
        for (int mt = 0; mt < 4; ++mt) {
          acc[mt][0] = __builtin_amdgcn_mfma_f32_16x16x32_bf16(af[mt], wfh[kk * 2 + 0], acc[mt][0], 0, 0, 0);
          acc[mt][1] = __builtin_amdgcn_mfma_f32_16x16x32_bf16(af[mt], wfh[kk * 2 + 1], acc[mt][1], 0, 0, 0);
        }
      }
    }

    // C layout: row m = 16*mt + 4*q + r, col n = 16*nt + ln
#pragma unroll
    for (int mt = 0; mt < 4; ++mt)
#pragma unroll
      for (int nt = 0; nt < 2; ++nt)
#pragma unroll
        for (int r = 0; r < 4; ++r)
          gp[w][16 * mt + 4 * q + r][16 * nt + ln] = acc[mt][nt][r];

    __syncthreads(); // also establishes: all 128 producer flags confirmed

    float hv[2];
#pragma unroll
    for (int s = 0; s < 2; ++s) {
      const int jj = 2 * jj0 + s;
      float iv = bsum[s][0], fv = bsum[s][1], gv = bsum[s][2], ov = bsum[s][3];
#pragma unroll
      for (int ww = 0; ww < 4; ++ww) {
        iv += gp[ww][eb][jj];
        fv += gp[ww][eb][8 + jj];
        gv += gp[ww][eb][16 + jj];
        ov += gp[ww][eb][24 + jj];
      }
      const float ig = sigm(iv);
      const float fg = sigm(fv);
      const float gg_ = tanha(gv);
      const float og = sigm(ov);
      const float c = fg * cst[s] + ig * gg_;
      cst[s] = c;
      hv[s] = og * tanha(c);
    }
    const unsigned packed_h = (unsigned)f2bf(hv[0]) | ((unsigned)f2bf(hv[1]) << 16);

    if (role == 0) {
      // publish h5 AND out5 (= h + x residual, fp32 math) in ONE window
      __hip_atomic_store((unsigned*)(hbuf5 + hidx), packed_h, __ATOMIC_RELAXED,
                         __HIP_MEMORY_SCOPE_AGENT);
      const float o0 = hv[0] + rres[0];
      const float o1 = hv[1] + rres[1];
      const unsigned po = (unsigned)f2bf(o0) | ((unsigned)f2bf(o1) << 16);
      __hip_atomic_store((unsigned*)(out5b + hidx), po, __ATOMIC_RELAXED,
                         __HIP_MEMORY_SCOPE_AGENT);
      asm volatile("s_waitcnt vmcnt(0)" ::: "memory");
      __syncthreads();
      if (tid == 0)
        __hip_atomic_store(flags5 + (size_t)t * GG + p, 1, __ATOMIC_RELAXED,
                           __HIP_MEMORY_SCOPE_AGENT);
    } else {
      __hip_atomic_store((unsigned*)(hbuf6 + hidx), packed_h, __ATOMIC_RELAXED,
                         __HIP_MEMORY_SCOPE_AGENT);
      asm volatile("s_waitcnt vmcnt(0)" ::: "memory");
      __syncthreads();
      if (tid == 0)
        __hip_atomic_store(flags6 + (size_t)t * GG + p, 1, __ATOMIC_RELAXED,
                           __HIP_MEMORY_SCOPE_AGENT);
      // ---- final out = h6 + out5 residual (off critical path; cached read
      // of own cols, published by L5 and confirmed via collective polls)
      const unsigned rb = *(const unsigned*)(out5b + hidx);
      const float o0 = hv[0] + bf2f((unsigned short)(rb & 0xffff));
      const float o1 = hv[1] + bf2f((unsigned short)(rb >> 16));
      float2v vo; vo[0] = o0; vo[1] = o1;
      *(float2v*)(out + tb + (size_t)eb * HH + p * 8 + 2 * jj0) = vo;
    }
  }
}

extern "C" void kernel_launch(void* const* d_in, const int* in_sizes, int n_in,
                              void* d_out, int out_size, void* d_ws, size_t ws_size,
                              hipStream_t stream) {
  const float* x    = (const float*)d_in[0];
  const float* wih5 = (const float*)d_in[1];
  const float* whh5 = (const float*)d_in[2];
  const float* bih5 = (const float*)d_in[3];
  const float* bhh5 = (const float*)d_in[4];
  const float* wih6 = (const float*)d_in[5];
  const float* whh6 = (const float*)d_in[6];
  const float* bih6 = (const float*)d_in[7];
  const float* bhh6 = (const float*)d_in[8];
  float* out = (float*)d_out;

  // ws (96.3 MB):
  //   [0,32M)   out5b : layer5 output bf16 blocked (layer6 x-input + residual)
  //   [32M,64M) hbuf5 : layer5 h history bf16 blocked
  //   [64M,96M) hbuf6 : layer6 h history bf16 blocked
  //   [96M,+256K) flags5 | flags6 (TT*GG ints each)
  char* ws = (char*)d_ws;
  unsigned short* out5b = (unsigned short*)(ws);
  unsigned short* hbuf5 = (unsigned short*)(ws + 33554432);
  unsigned short* hbuf6 = (unsigned short*)(ws + 67108864);
  int* flags            = (int*)(ws + 100663296);
  int* flags5 = flags;
  int* flags6 = flags + TT * GG;

  hipMemsetAsync(flags, 0, 2 * TT * GG * sizeof(int), stream);

  lstm2_fused<<<dim3(2 * GG), dim3(256), 0, stream>>>(
      x, wih5, whh5, bih5, bhh5, wih6, whh6, bih6, bhh6,
      out5b, hbuf5, hbuf6, out, flags5, flags6);
}

// Round 3
// 4920.504 us; speedup vs baseline: 1.0119x; 1.0119x over previous
//
#include <hip/hip_runtime.h>

// Residual 2-layer LSTM, T=256 B=64 H=1024, fp32 io, bf16 MFMA compute.
//
// R6 = R4 (fused 256-WG persistent kernel, layer5 on WGs 0-127, layer6 on
// WGs 128-255, software-pipelined one step apart; wave0-only polling with
// release __syncthreads, s_sleep(2)) + ONE change kept from R5:
//
//  - SINGLE flag per layer-5 step: out5b (= h + x residual, fp32 math, with
//    the residual PREFETCHED at step start) is stored in the SAME
//    vmcnt(0)+barrier window as h5, under flags5[t]. flagsO is gone; L5's
//    second publish block (extra drain+barrier+flag) is gone; out5[t]
//    becomes visible to L6 earlier.
//
// R5's per-wave subset polling + s_sleep(1) are REVERTED: the gp barrier
// re-couples all 4 waves each step (straggler set stayed 128), while poller
// count went 256->1024 and poll rate 2x -> ~8x agent-scope traffic into the
// hot LLC flag lines that producers must store to. R5 cost 5 us/step; this
// restores R4's quiet poll structure.
//
// Coherence (one dispatch, no boundary flush):
//  - h5/h6/out5b written with AGENT-scope 4B stores + vmcnt(0) drain before
//    the flag store. Reader-side cached loads are safe: addresses are virgin
//    within the dispatch (written once agent-scope -> LLC, read after).

#define TT 256
#define BB 64
#define HH 1024
#define GG 128
#define BH (BB * HH)

typedef __attribute__((ext_vector_type(8))) short short8;
typedef __attribute__((ext_vector_type(4))) float float4v;
typedef __attribute__((ext_vector_type(2))) float float2v;

__device__ __forceinline__ unsigned short f2bf(float f) {
  unsigned u = __builtin_bit_cast(unsigned, f);
  u += 0x7fffu + ((u >> 16) & 1u);
  return (unsigned short)(u >> 16);
}
__device__ __forceinline__ float bf2f(unsigned short s) {
  unsigned u = ((unsigned)s) << 16;
  return __builtin_bit_cast(float, u);
}
__device__ __forceinline__ float fexp2(float x) { return __builtin_amdgcn_exp2f(x); }
__device__ __forceinline__ float frcp(float x) { return __builtin_amdgcn_rcpf(x); }
__device__ __forceinline__ float sigm(float x) {
  return frcp(1.0f + fexp2(-1.4426950408889634f * x));
}
__device__ __forceinline__ float tanha(float x) {
  return 1.0f - 2.0f * frcp(1.0f + fexp2(2.8853900817779268f * x));
}

__global__ __launch_bounds__(256, 1) void lstm2_fused(
    const float* __restrict__ x,
    const float* __restrict__ wih5, const float* __restrict__ whh5,
    const float* __restrict__ bih5, const float* __restrict__ bhh5,
    const float* __restrict__ wih6, const float* __restrict__ whh6,
    const float* __restrict__ bih6, const float* __restrict__ bhh6,
    unsigned short* __restrict__ out5b, unsigned short* __restrict__ hbuf5,
    unsigned short* __restrict__ hbuf6, float* __restrict__ out,
    int* __restrict__ flags5, int* __restrict__ flags6) {
  const int role = (int)(blockIdx.x >> 7); // 0 = layer5, 1 = layer6
  const int p = (int)(blockIdx.x & 127);   // column block (8 h-cols)
  const int tid = threadIdx.x;
  const int w = tid >> 6;
  const int lane = tid & 63;
  const int ln = lane & 15;
  const int q = lane >> 4;

  __shared__ float gp[4][BB][35];

  const float* wih = role ? wih6 : wih5;
  const float* whh = role ? whh6 : whh5;
  const float* bih = role ? bih6 : bih5;
  const float* bhh = role ? bhh6 : bhh5;
  unsigned short* hbuf = role ? hbuf6 : hbuf5;
  int* hflags = role ? flags6 : flags5;

  // ---- persistent weight fragments: this wave covers k in [256w, 256w+256)
  // wf[kk*2+nt]: n = 16*nt+ln, k = 256*w + kk*32 + 8*q + j
  short8 wfx[16], wfh[16];
#pragma unroll
  for (int kk = 0; kk < 8; ++kk) {
#pragma unroll
    for (int nt = 0; nt < 2; ++nt) {
      const int n = 16 * nt + ln;
      const int gidx = (n >> 3) * HH + p * 8 + (n & 7); // gate order i,f,g,o
      const int k0 = 256 * w + kk * 32 + 8 * q;
      const float* sx = wih + (size_t)gidx * HH + k0;
      const float* sh = whh + (size_t)gidx * HH + k0;
      short8 vx, vh;
#pragma unroll
      for (int j = 0; j < 8; ++j) { vx[j] = (short)f2bf(sx[j]); vh[j] = (short)f2bf(sh[j]); }
      wfx[kk * 2 + nt] = vx;
      wfh[kk * 2 + nt] = vh;
    }
  }

  // ---- elementwise state: thread owns (b=lane, cols 2w and 2w+1)
  const int eb = lane;
  const int jj0 = w;
  float bsum[2][4];
#pragma unroll
  for (int s = 0; s < 2; ++s) {
    const int jj = 2 * jj0 + s;
#pragma unroll
    for (int gt = 0; gt < 4; ++gt) {
      const int gidx = gt * HH + p * 8 + jj;
      bsum[s][gt] = bih[gidx] + bhh[gidx];
    }
  }
  float cst[2] = {0.f, 0.f};

  // ---- A-operand offsets
  size_t rh[4];  // blocked bf16 layout [t][col>>3][b][col&7]
  size_t rxf[4]; // fp32 row-major [t][b][h] (layer5 x)
#pragma unroll
  for (int mt = 0; mt < 4; ++mt) {
    rh[mt] = (size_t)(16 * mt + ln) * 8 + (size_t)(256 * w + 8 * q) * 64;
    rxf[mt] = (size_t)(16 * mt + ln) * HH + (size_t)(256 * w + 8 * q);
  }

  for (int t = 0; t < TT; ++t) {
    float4v acc[4][2];
#pragma unroll
    for (int mt = 0; mt < 4; ++mt)
#pragma unroll
      for (int nt = 0; nt < 2; ++nt)
        acc[mt][nt] = (float4v){0.f, 0.f, 0.f, 0.f};

    const size_t tb = (size_t)t * BH;
    const size_t hidx = tb + (size_t)p * 512 + (size_t)eb * 8 + 2 * jj0;
    float2v rres; // layer5 x-residual, prefetched before the publish window

    if (role == 0) {
      // residual prefetch (read-only, no cross-WG dependency; arrives
      // during the x-part, so the publish window never waits on it)
      rres = *(const float2v*)(x + tb + (size_t)eb * HH + p * 8 + 2 * jj0);
      // ---- layer5 x-part: fp32 x, cvt on the fly (no cross-WG dependency;
      // overlaps other WGs' tails -> VALU hides in straggler slack)
      const float* Xb = x + tb;
#pragma unroll
      for (int kk = 0; kk < 8; ++kk) {
        short8 af[4];
#pragma unroll
        for (int mt = 0; mt < 4; ++mt) {
          const float* sx = Xb + rxf[mt] + 32 * kk;
          const float4v a = *(const float4v*)sx;
          const float4v b = *(const float4v*)(sx + 4);
          short8 v;
          v[0] = (short)f2bf(a[0]); v[1] = (short)f2bf(a[1]);
          v[2] = (short)f2bf(a[2]); v[3] = (short)f2bf(a[3]);
          v[4] = (short)f2bf(b[0]); v[5] = (short)f2bf(b[1]);
          v[6] = (short)f2bf(b[2]); v[7] = (short)f2bf(b[3]);
          af[mt] = v;
        }
#pragma unroll
        for (int mt = 0; mt < 4; ++mt) {
          acc[mt][0] = __builtin_amdgcn_mfma_f32_16x16x32_bf16(af[mt], wfx[kk * 2 + 0], acc[mt][0], 0, 0, 0);
          acc[mt][1] = __builtin_amdgcn_mfma_f32_16x16x32_bf16(af[mt], wfx[kk * 2 + 1], acc[mt][1], 0, 0, 0);
        }
      }
      // gate h-part on all 128 layer-5 WGs having published h5[t-1]
      if (t > 0) {
        if (w == 0) {
          int* fl = flags5 + (size_t)(t - 1) * GG;
          for (;;) {
            const int a0 = __hip_atomic_load(fl + lane, __ATOMIC_RELAXED, __HIP_MEMORY_SCOPE_AGENT);
            const int a1 = __hip_atomic_load(fl + 64 + lane, __ATOMIC_RELAXED, __HIP_MEMORY_SCOPE_AGENT);
            if (__all((a0 != 0) & (a1 != 0))) break;
            __builtin_amdgcn_s_sleep(2);
          }
        }
        __builtin_amdgcn_fence(__ATOMIC_ACQUIRE, "workgroup"); // compiler order only
        __syncthreads();
      }
    } else {
      // ---- layer6 gate: out5[t] ready (all 128, via flags5[t] -- out5b is
      // published in the same window as h5) AND own h6[t-1] ready
      if (w == 0) {
        int* fo = flags5 + (size_t)t * GG;
        int* fh = flags6 + (size_t)(t > 0 ? t - 1 : 0) * GG;
        for (;;) {
          const int a0 = __hip_atomic_load(fo + lane, __ATOMIC_RELAXED, __HIP_MEMORY_SCOPE_AGENT);
          const int a1 = __hip_atomic_load(fo + 64 + lane, __ATOMIC_RELAXED, __HIP_MEMORY_SCOPE_AGENT);
          int ok = (a0 != 0) & (a1 != 0);
          if (t > 0) {
            const int b0 = __hip_atomic_load(fh + lane, __ATOMIC_RELAXED, __HIP_MEMORY_SCOPE_AGENT);
            const int b1 = __hip_atomic_load(fh + 64 + lane, __ATOMIC_RELAXED, __HIP_MEMORY_SCOPE_AGENT);
            ok &= (b0 != 0) & (b1 != 0);
          }
          if (__all(ok)) break;
          __builtin_amdgcn_s_sleep(2);
        }
      }
      __builtin_amdgcn_fence(__ATOMIC_ACQUIRE, "workgroup"); // compiler order only
      __syncthreads();
      // ---- layer6 x-part: out5b blocked bf16 (cached; virgin addrs -> LLC-fresh)
      const unsigned short* Ab = out5b + tb;
#pragma unroll
      for (int kk = 0; kk < 8; ++kk) {
        short8 af[4];
#pragma unroll
        for (int mt = 0; mt < 4; ++mt)
          af[mt] = *(const short8*)(Ab + rh[mt] + (size_t)kk * 2048);
#pragma unroll
        for (int mt = 0; mt < 4; ++mt) {
          acc[mt][0] = __builtin_amdgcn_mfma_f32_16x16x32_bf16(af[mt], wfx[kk * 2 + 0], acc[mt][0], 0, 0, 0);
          acc[mt][1] = __builtin_amdgcn_mfma_f32_16x16x32_bf16(af[mt], wfx[kk * 2 + 1], acc[mt][1], 0, 0, 0);
        }
      }
    }

    // ---- h-part (common; gating already done per-role above)
    if (t > 0) {
      const unsigned short* Hb = hbuf + (size_t)(t - 1) * BH;
#pragma unroll
      for (int kk = 0; kk < 8; ++kk) {
        short8 af[4];
#pragma unroll
        for (int mt = 0; mt < 4; ++mt)
          af[mt] = *(const short8*)(Hb + rh[mt] + (size_t)kk * 2048); // cached
#pragma unroll
        for (int mt = 0; mt < 4; ++mt) {
          acc[mt][0] = __builtin_amdgcn_mfma_f32_16x16x32_bf16(af[mt], wfh[kk * 2 + 0], acc[mt][0], 0, 0, 0);
          acc[mt][1] = __builtin_amdgcn_mfma_f32_16x16x32_bf16(af[mt], wfh[kk * 2 + 1], acc[mt][1], 0, 0, 0);
        }
      }
    }

    // C layout: row m = 16*mt + 4*q + r, col n = 16*nt + ln
#pragma unroll
    for (int mt = 0; mt < 4; ++mt)
#pragma unroll
      for (int nt = 0; nt < 2; ++nt)
#pragma unroll
        for (int r = 0; r < 4; ++r)
          gp[w][16 * mt + 4 * q + r][16 * nt + ln] = acc[mt][nt][r];

    __syncthreads();

    float hv[2];
#pragma unroll
    for (int s = 0; s < 2; ++s) {
      const int jj = 2 * jj0 + s;
      float iv = bsum[s][0], fv = bsum[s][1], gv = bsum[s][2], ov = bsum[s][3];
#pragma unroll
      for (int ww = 0; ww < 4; ++ww) {
        iv += gp[ww][eb][jj];
        fv += gp[ww][eb][8 + jj];
        gv += gp[ww][eb][16 + jj];
        ov += gp[ww][eb][24 + jj];
      }
      const float ig = sigm(iv);
      const float fg = sigm(fv);
      const float gg_ = tanha(gv);
      const float og = sigm(ov);
      const float c = fg * cst[s] + ig * gg_;
      cst[s] = c;
      hv[s] = og * tanha(c);
    }
    const unsigned packed_h = (unsigned)f2bf(hv[0]) | ((unsigned)f2bf(hv[1]) << 16);

    if (role == 0) {
      // publish h5 AND out5 (= h + x residual, fp32 math) in ONE window
      __hip_atomic_store((unsigned*)(hbuf5 + hidx), packed_h, __ATOMIC_RELAXED,
                         __HIP_MEMORY_SCOPE_AGENT);
      const float o0 = hv[0] + rres[0];
      const float o1 = hv[1] + rres[1];
      const unsigned po = (unsigned)f2bf(o0) | ((unsigned)f2bf(o1) << 16);
      __hip_atomic_store((unsigned*)(out5b + hidx), po, __ATOMIC_RELAXED,
                         __HIP_MEMORY_SCOPE_AGENT);
      asm volatile("s_waitcnt vmcnt(0)" ::: "memory"); // both stores at coherent point
      __syncthreads();
      if (tid == 0)
        __hip_atomic_store(flags5 + (size_t)t * GG + p, 1, __ATOMIC_RELAXED,
                           __HIP_MEMORY_SCOPE_AGENT);
    } else {
      __hip_atomic_store((unsigned*)(hbuf6 + hidx), packed_h, __ATOMIC_RELAXED,
                         __HIP_MEMORY_SCOPE_AGENT);
      asm volatile("s_waitcnt vmcnt(0)" ::: "memory");
      __syncthreads();
      if (tid == 0)
        __hip_atomic_store(flags6 + (size_t)t * GG + p, 1, __ATOMIC_RELAXED,
                           __HIP_MEMORY_SCOPE_AGENT);
      // ---- final out = h6 + out5 residual (off the inter-WG critical path;
      // cached read of own cols, published under flags5[t] which this WG
      // already confirmed before its x-part)
      const unsigned rb = *(const unsigned*)(out5b + hidx);
      const float o0 = hv[0] + bf2f((unsigned short)(rb & 0xffff));
      const float o1 = hv[1] + bf2f((unsigned short)(rb >> 16));
      float2v vo; vo[0] = o0; vo[1] = o1;
      *(float2v*)(out + tb + (size_t)eb * HH + p * 8 + 2 * jj0) = vo;
    }
  }
}

extern "C" void kernel_launch(void* const* d_in, const int* in_sizes, int n_in,
                              void* d_out, int out_size, void* d_ws, size_t ws_size,
                              hipStream_t stream) {
  const float* x    = (const float*)d_in[0];
  const float* wih5 = (const float*)d_in[1];
  const float* whh5 = (const float*)d_in[2];
  const float* bih5 = (const float*)d_in[3];
  const float* bhh5 = (const float*)d_in[4];
  const float* wih6 = (const float*)d_in[5];
  const float* whh6 = (const float*)d_in[6];
  const float* bih6 = (const float*)d_in[7];
  const float* bhh6 = (const float*)d_in[8];
  float* out = (float*)d_out;

  // ws (96.3 MB):
  //   [0,32M)   out5b : layer5 output bf16 blocked (layer6 x-input + residual)
  //   [32M,64M) hbuf5 : layer5 h history bf16 blocked
  //   [64M,96M) hbuf6 : layer6 h history bf16 blocked
  //   [96M,+256K) flags5 | flags6 (TT*GG ints each)
  char* ws = (char*)d_ws;
  unsigned short* out5b = (unsigned short*)(ws);
  unsigned short* hbuf5 = (unsigned short*)(ws + 33554432);
  unsigned short* hbuf6 = (unsigned short*)(ws + 67108864);
  int* flags            = (int*)(ws + 100663296);
  int* flags5 = flags;
  int* flags6 = flags + TT * GG;

  hipMemsetAsync(flags, 0, 2 * TT * GG * sizeof(int), stream);

  lstm2_fused<<<dim3(2 * GG), dim3(256), 0, stream>>>(
      x, wih5, whh5, bih5, bhh5, wih6, whh6, bih6, bhh6,
      out5b, hbuf5, hbuf6, out, flags5, flags6);
}